// Round 13
// baseline (479.952 us; speedup 1.0000x reference)
//
#include <hip/hip_runtime.h>

typedef __attribute__((ext_vector_type(8))) _Float16 half8;
typedef __attribute__((ext_vector_type(4))) float f32x4;

#define N1_ 100000
#define N2_ 200000
#define N3_ 300000
#define N4_ 400000

typedef __attribute__((address_space(1))) const void gconst_t;
typedef __attribute__((address_space(3))) void lds_t;

#define MEMFENCE() asm volatile("" ::: "memory")

__device__ __forceinline__ unsigned short f2h_bits(float x) {
  union { _Float16 h; unsigned short u; } cv;
  cv.h = (_Float16)x;
  return cv.u;
}

__device__ __forceinline__ f32x4 mfma16(half8 a, half8 b, f32x4 c) {
  return __builtin_amdgcn_mfma_f32_16x16x32_f16(a, b, c, 0, 0, 0);
}

// ---- convert h (fp32) -> fp16 bits --------------------------------------
__global__ void cvt_h_kernel(const float* __restrict__ h,
                             unsigned short* __restrict__ hf, int n4) {
  int i = blockIdx.x * blockDim.x + threadIdx.x;
  if (i >= n4) return;
  float4 v = reinterpret_cast<const float4*>(h)[i];
  ushort4 o;
  o.x = f2h_bits(v.x); o.y = f2h_bits(v.y);
  o.z = f2h_bits(v.z); o.w = f2h_bits(v.w);
  reinterpret_cast<ushort4*>(hf)[i] = o;
}

// ---- pack weights into MFMA B-fragment order ----------------------------
// packed[kt*4096 + nt*512 + lane*8 + j] = W[kt*32 + (lane>>4)*8 + j][nt*16 + (lane&15)]
struct PackInfo {
  const float* W[12];
  int kt_base[13];
  int out_off[12];
};

__global__ void pack_w_kernel(PackInfo info, unsigned short* __restrict__ pw) {
  int b = blockIdx.x;
  int lane = threadIdx.x;  // 64 threads
  int m = 0;
  while (m < 11 && b >= info.kt_base[m + 1]) ++m;
  int kt = b - info.kt_base[m];
  const float* W = info.W[m];
  int lr = lane & 15, kb = lane >> 4;
  unsigned short* outp = pw + info.out_off[m] + (size_t)kt * 4096 + lane * 8;
  #pragma unroll
  for (int nt = 0; nt < 8; ++nt) {
    #pragma unroll
    for (int j = 0; j < 8; ++j) {
      int krow = kt * 32 + kb * 8 + j;
      int col = nt * 16 + lr;
      outp[nt * 512 + j] = f2h_bits(W[(size_t)krow * 128 + col]);
    }
  }
}

// ---- main level kernel --------------------------------------------------
// Round-6 structure (4 waves x 1 tile, 2-phase weight staging, 48/32 KB LDS,
// 12 waves/CU) with ONE change: layer-0 A-fragments are BULK-GATHERED into
// per-wave LDS via global_load_lds (per-lane global src, wave-uniform LDS
// dst + lane*16). A seg-pair chunk {c, K-1-c} (8x1KB DMAs) is issued up
// front and drained ONCE -- gather latency paid 1-2x/tile instead of
// ~16x (per-phase vmcnt(0) drain was the r6 equilibrium's exposed term).
// Gather region unions with act (temporally disjoint, per-wave private).
// Dedup preserved: resident fragments serve fwd+bwd by LDS re-read.
// Zero prefetch registers; only __syncthreads -> deterministic.
template <int K, int NHEAD>
__global__ __launch_bounds__(256, (K == 1) ? 4 : 3) void level_kernel(
    const unsigned short* __restrict__ hf,
    const int* __restrict__ idx,
    const unsigned short* __restrict__ pw,  // packed W0|W1|W2 (fp16 bits)
    const float* __restrict__ b0, const float* __restrict__ b1,
    const float* __restrict__ b2,
    const float* __restrict__ hw0, const float* __restrict__ hb0,
    float* __restrict__ out0,
    const float* __restrict__ hw1, const float* __restrict__ hb1,
    float* __restrict__ out1,
    const float* __restrict__ hw2, const float* __restrict__ hb2,
    float* __restrict__ out2,
    int N) {
  constexpr int NDIR = (K > 1) ? 2 : 1;
  constexpr int KT0 = 4 * K;
  constexpr int NC = (K + 1) / 2;            // seg-pair chunks
  constexpr int GRB = (K == 1) ? 4096 : 8192;  // gather/act region per wave
  constexpr int SMEM_SZ = 16384 + 4 * GRB;   // 48 KB (K>=2) / 32 KB (K==1)

  __shared__ __align__(16) unsigned char smem[SMEM_SZ];

  const int lane = threadIdx.x & 63;
  const int wid = threadIdx.x >> 6;   // 0..3
  const int lrow = lane & 15;
  const int kb = lane >> 4;

  unsigned short* const bst = reinterpret_cast<unsigned short*>(smem);
  unsigned char* const gbase = smem + 16384 + wid * GRB;  // per-wave private

  int tile = blockIdx.x * 4 + wid;
  const int maxtile = N / 16 - 1;
  const bool wr = (tile <= maxtile);
  if (!wr) tile = maxtile;  // clamp: all waves hit barriers, only writers store

  int src[K];
  #pragma unroll
  for (int s = 0; s < K; ++s)
    src[s] = (K == 1) ? (tile * 16 + lrow)
                      : idx[(size_t)(tile * 16 + lrow) * K + s];

  // stage one 8 KB weight slab into bst[buf]; each wave DMAs 2x1KB width-16
  auto stage = [&](int buf, const unsigned short* slab) {
    const unsigned short* g = slab + (wid * 2) * 512 + lane * 8;
    unsigned short* l = bst + buf * 4096 + (wid * 2) * 512;
    __builtin_amdgcn_global_load_lds((gconst_t*)g, (lds_t*)l, 16, 0, 0);
    __builtin_amdgcn_global_load_lds((gconst_t*)(g + 512), (lds_t*)(l + 512), 16, 0, 0);
  };

  // gather DMA: fragment (seg,sub) -> slot (1 KB). Global src per-lane,
  // LDS dst wave-uniform (HW writes lane l at dst + l*16).
  auto dma_gather = [&](int seg, int sub, int slot) {
    const unsigned short* g = hf + (size_t)src[seg] * 128 + sub * 32 + kb * 8;
    __builtin_amdgcn_global_load_lds((gconst_t*)g, (lds_t*)(gbase + slot * 1024),
                                     16, 0, 0);
  };
  // chunk c holds segs sA=c (slots 0-3) and sB=K-1-c (slots 4-7)
  auto issue_chunk = [&](int c) {
    #pragma unroll
    for (int sub = 0; sub < 4; ++sub) {
      dma_gather(c, sub, sub);
      if (c != K - 1 - c) dma_gather(K - 1 - c, sub, 4 + sub);
    }
  };
  auto readfrag = [&](int slot) -> half8 {
    return *reinterpret_cast<const half8*>(gbase + slot * 1024 + lane * 16);
  };

  f32x4 acc[NDIR][8];
  auto zero_acc = [&]() {
    #pragma unroll
    for (int d = 0; d < NDIR; ++d)
      #pragma unroll
      for (int nt = 0; nt < 8; ++nt) acc[d][nt] = f32x4{0.f, 0.f, 0.f, 0.f};
  };

  auto mfma_phase = [&](int buf, half8 af, half8 ab) {
    #pragma unroll
    for (int nt = 0; nt < 8; ++nt) {
      half8 bq = *reinterpret_cast<const half8*>(bst + buf * 4096 + nt * 512 + lane * 8);
      acc[0][nt] = mfma16(af, bq, acc[0][nt]);
      if constexpr (NDIR == 2) acc[1][nt] = mfma16(ab, bq, acc[1][nt]);
    }
  };

  // layers 1/2: A from per-wave activation LDS (XOR-swizzled rows);
  // act region reuses the gather region (consumed by then).
  auto actA = [&](int d, int kt) -> half8 {
    unsigned off = (unsigned)(lrow * 256 + (kt * 32 + kb * 8) * 2) ^
                   ((unsigned)(lrow & 7) << 4);
    return *reinterpret_cast<const half8*>(gbase + d * 4096 + off);
  };
  auto store_act = [&](int d, const float* bias) {
    unsigned char* base = gbase + d * 4096;
    #pragma unroll
    for (int nt = 0; nt < 8; ++nt) {
      float bv = bias[nt * 16 + lrow];
      #pragma unroll
      for (int r = 0; r < 4; ++r) {
        float v = fmaxf(acc[d][nt][r] + bv, 0.f);
        int trow = 4 * kb + r;
        unsigned off = (unsigned)(trow * 256 + (nt * 16 + lrow) * 2) ^
                       ((unsigned)(trow & 7) << 4);
        *reinterpret_cast<unsigned short*>(base + off) = f2h_bits(v);
      }
    }
  };

  zero_acc();

  const unsigned short* w1 = pw + (size_t)KT0 * 4096;

  // ================= layer 0 =============================================
  // prologue: bulk-issue chunk 0 gathers + first weight slab, drain once.
  issue_chunk(0);
  stage(0, pw);  // slab (seg 0, sub 0)
  __syncthreads();

  int cur = 0;
  #pragma unroll
  for (int c = 0; c < NC; ++c) {
    const bool selfpair = (c == K - 1 - c);
    const int pc = selfpair ? 4 : 8;
    #pragma unroll
    for (int q = 0; q < pc; ++q) {
      // phase -> (seg, sub, fwd slot, bwd slot)
      int seg, sub, fs, bs;
      if (selfpair) { seg = c; sub = q; fs = q; bs = q; }
      else {
        int i = q >> 1, ab = q & 1;
        seg = ab ? (K - 1 - c) : c; sub = i;
        fs = ab ? 4 + i : i; bs = ab ? i : 4 + i;
      }
      (void)seg;
      half8 af = readfrag(fs);
      half8 abf{};
      if constexpr (NDIR == 2) abf = readfrag(bs);

      // stage next weight slab (double-buffered)
      if (q + 1 < pc) {
        int i2 = selfpair ? (q + 1) : ((q + 1) >> 1);
        int ab2 = selfpair ? 0 : ((q + 1) & 1);
        int seg2 = selfpair ? c : (ab2 ? (K - 1 - c) : c);
        stage(cur ^ 1, pw + (size_t)(seg2 * 4 + i2) * 4096);
      } else if (c + 1 < NC) {
        stage(cur ^ 1, pw + (size_t)((c + 1) * 4) * 4096);  // (sA(c+1), 0)
      } else {
        stage(cur ^ 1, w1);  // layer-1 slab 0
      }
      MEMFENCE();
      mfma_phase(cur, af, abf);
      MEMFENCE();
      // chunk reload: after this chunk's last MFMAs (region is per-wave
      // private and fully consumed); drained by this phase's barrier.
      if (q == pc - 1 && c + 1 < NC) issue_chunk(c + 1);
      __syncthreads();
      cur ^= 1;
    }
  }

  #pragma unroll
  for (int d = 0; d < NDIR; ++d) store_act(d, b0);

  // ================= layers 1 and 2 (round-6 8KB phases) =================
  #pragma unroll 1
  for (int layer = 1; layer <= 2; ++layer) {
    const unsigned short* w = (layer == 1) ? w1 : w1 + 16384;
    zero_acc();
    for (int kt = 0; kt < 4; ++kt) {
      if (kt + 1 < 4) stage(cur ^ 1, w + (size_t)(kt + 1) * 4096);
      else if (layer == 1) stage(cur ^ 1, w1 + 16384);  // layer-2 slab 0
      half8 a[NDIR];
      #pragma unroll
      for (int d = 0; d < NDIR; ++d) a[d] = actA(d, kt);
      #pragma unroll
      for (int nt = 0; nt < 8; ++nt) {
        half8 bq = *reinterpret_cast<const half8*>(bst + cur * 4096 + nt * 512 + lane * 8);
        #pragma unroll
        for (int d = 0; d < NDIR; ++d) acc[d][nt] = mfma16(a[d], bq, acc[d][nt]);
      }
      if (!(layer == 2 && kt == 3)) {  // last slab: no one reuses bst
        __syncthreads();
        cur ^= 1;
      }
    }
    if (layer == 1) {
      #pragma unroll
      for (int d = 0; d < NDIR; ++d) store_act(d, b1);
    }
  }

  // ================= epilogue: bias+relu(+pool), heads ===================
  f32x4 y[8];
  #pragma unroll
  for (int nt = 0; nt < 8; ++nt) {
    float bv = b2[nt * 16 + lrow];
    #pragma unroll
    for (int r = 0; r < 4; ++r) {
      float v = fmaxf(acc[0][nt][r] + bv, 0.f);
      if constexpr (NDIR == 2) v += fmaxf(acc[1][nt][r] + bv, 0.f);
      y[nt][r] = v;
    }
  }

  const float* hws[3] = {hw0, hw1, hw2};
  const float* hbs[3] = {hb0, hb1, hb2};
  float* outs[3] = {out0, out1, out2};
  #pragma unroll
  for (int hd = 0; hd < NHEAD; ++hd) {
    float p[4] = {0.f, 0.f, 0.f, 0.f};
    #pragma unroll
    for (int nt = 0; nt < 8; ++nt) {
      float w = hws[hd][nt * 16 + lrow];
      #pragma unroll
      for (int r = 0; r < 4; ++r) p[r] += y[nt][r] * w;
    }
    #pragma unroll
    for (int m = 1; m < 16; m <<= 1) {
      #pragma unroll
      for (int r = 0; r < 4; ++r) p[r] += __shfl_xor(p[r], m, 64);
    }
    if (wr && lrow < 4) {
      float pv = (lrow == 0) ? p[0] : (lrow == 1) ? p[1] : (lrow == 2) ? p[2] : p[3];
      outs[hd][tile * 16 + 4 * kb + lrow] = pv + hbs[hd][0];
    }
  }
}

// -------------------------------------------------------------------------
extern "C" void kernel_launch(void* const* d_in, const int* in_sizes, int n_in,
                              void* d_out, int out_size, void* d_ws, size_t ws_size,
                              hipStream_t stream) {
  (void)in_sizes; (void)n_in; (void)out_size;

  const float* h = (const float*)d_in[0];
  const int* idx2 = (const int*)d_in[1];
  const int* idx3 = (const int*)d_in[2];
  const int* idx4 = (const int*)d_in[3];

  const float* sW[4][3];
  const float* sb[4][3];
  for (int L = 0; L < 4; ++L)
    for (int j = 0; j < 3; ++j) {
      sW[L][j] = (const float*)d_in[4 + L * 6 + j * 2];
      sb[L][j] = (const float*)d_in[4 + L * 6 + j * 2 + 1];
    }
  // heads: h1_sigma, h1_epsilon, h1_q, h2_k, h2_eq, h3_k, h3_eq, h4_k, h4_eq
  const float* hW[9];
  const float* hB[9];
  for (int i = 0; i < 9; ++i) {
    hW[i] = (const float*)d_in[28 + i * 2];
    hB[i] = (const float*)d_in[28 + i * 2 + 1];
  }

  // workspace: fp16 h (12.8M elems) + packed weights (294912 elems)
  size_t need = ((size_t)N1_ * 128 + 294912) * 2;
  if (ws_size < need) return;
  unsigned short* hf = (unsigned short*)d_ws;
  unsigned short* pw = hf + (size_t)N1_ * 128;

  cvt_h_kernel<<<(N1_ * 128 / 4 + 255) / 256, 256, 0, stream>>>(h, hf, N1_ * 128 / 4);

  PackInfo pi;
  const int din[12] = {128, 128, 128, 256, 128, 128, 384, 128, 128, 512, 128, 128};
  int ktb = 0, ooff = 0;
  for (int m = 0; m < 12; ++m) {
    pi.W[m] = sW[m / 3][m % 3];
    pi.kt_base[m] = ktb;
    pi.out_off[m] = ooff;
    ktb += din[m] / 32;
    ooff += din[m] * 128;
  }
  pi.kt_base[12] = ktb;  // 72
  pack_w_kernel<<<ktb, 64, 0, stream>>>(pi, pw);

  float* out = (float*)d_out;
  float* o_sigma = out;
  float* o_eps = out + N1_;
  float* o_q = out + 2 * N1_;
  float* o_k2 = out + 3 * N1_;
  float* o_eq2 = o_k2 + N2_;
  float* o_k3 = o_eq2 + N2_;
  float* o_eq3 = o_k3 + N3_;
  float* o_k4 = o_eq3 + N3_;
  float* o_eq4 = o_k4 + N4_;

  // grid: each block covers 4 waves x 1 tile = 64 rows
  level_kernel<1, 3><<<(N1_ / 16 + 3) / 4, 256, 0, stream>>>(
      hf, nullptr, pw + pi.out_off[0], sb[0][0], sb[0][1], sb[0][2],
      hW[0], hB[0], o_sigma, hW[1], hB[1], o_eps, hW[2], hB[2], o_q, N1_);
  level_kernel<2, 2><<<(N2_ / 16 + 3) / 4, 256, 0, stream>>>(
      hf, idx2, pw + pi.out_off[3], sb[1][0], sb[1][1], sb[1][2],
      hW[3], hB[3], o_k2, hW[4], hB[4], o_eq2, nullptr, nullptr, nullptr, N2_);
  level_kernel<3, 2><<<(N3_ / 16 + 3) / 4, 256, 0, stream>>>(
      hf, idx3, pw + pi.out_off[6], sb[2][0], sb[2][1], sb[2][2],
      hW[5], hB[5], o_k3, hW[6], hB[6], o_eq3, nullptr, nullptr, nullptr, N3_);
  level_kernel<4, 2><<<(N4_ / 16 + 3) / 4, 256, 0, stream>>>(
      hf, idx4, pw + pi.out_off[9], sb[3][0], sb[3][1], sb[3][2],
      hW[7], hB[7], o_k4, hW[8], hB[8], o_eq4, nullptr, nullptr, nullptr, N4_);
}

// Round 14
// 446.775 us; speedup vs baseline: 1.0743x; 1.0743x over previous
//
#include <hip/hip_runtime.h>

typedef __attribute__((ext_vector_type(8))) _Float16 half8;
typedef __attribute__((ext_vector_type(4))) float f32x4;

#define N1_ 100000
#define N2_ 200000
#define N3_ 300000
#define N4_ 400000

typedef __attribute__((address_space(1))) const void gconst_t;
typedef __attribute__((address_space(3))) void lds_t;

__device__ __forceinline__ unsigned short f2h_bits(float x) {
  union { _Float16 h; unsigned short u; } cv;
  cv.h = (_Float16)x;
  return cv.u;
}

__device__ __forceinline__ f32x4 mfma16(half8 a, half8 b, f32x4 c) {
  return __builtin_amdgcn_mfma_f32_16x16x32_f16(a, b, c, 0, 0, 0);
}

// ---- convert h (fp32) -> fp16 bits --------------------------------------
__global__ void cvt_h_kernel(const float* __restrict__ h,
                             unsigned short* __restrict__ hf, int n4) {
  int i = blockIdx.x * blockDim.x + threadIdx.x;
  if (i >= n4) return;
  float4 v = reinterpret_cast<const float4*>(h)[i];
  ushort4 o;
  o.x = f2h_bits(v.x); o.y = f2h_bits(v.y);
  o.z = f2h_bits(v.z); o.w = f2h_bits(v.w);
  reinterpret_cast<ushort4*>(hf)[i] = o;
}

// ---- pack weights into MFMA B-fragment order ----------------------------
// packed[kt*4096 + nt*512 + lane*8 + j] = W[kt*32 + (lane>>4)*8 + j][nt*16 + (lane&15)]
struct PackInfo {
  const float* W[12];
  int kt_base[13];
  int out_off[12];
};

__global__ void pack_w_kernel(PackInfo info, unsigned short* __restrict__ pw) {
  int b = blockIdx.x;
  int lane = threadIdx.x;  // 64 threads
  int m = 0;
  while (m < 11 && b >= info.kt_base[m + 1]) ++m;
  int kt = b - info.kt_base[m];
  const float* W = info.W[m];
  int lr = lane & 15, kb = lane >> 4;
  unsigned short* outp = pw + info.out_off[m] + (size_t)kt * 4096 + lane * 8;
  #pragma unroll
  for (int nt = 0; nt < 8; ++nt) {
    #pragma unroll
    for (int j = 0; j < 8; ++j) {
      int krow = kt * 32 + kb * 8 + j;
      int col = nt * 16 + lr;
      outp[nt * 512 + j] = f2h_bits(W[(size_t)krow * 128 + col]);
    }
  }
}

// ---- main level kernel --------------------------------------------------
// Round-6 codegen shape (4 waves x 1 tile, compact runtime phase loops,
// 2-phase weight staging, 48/32 KB LDS, 12 waves/CU) + round-13 mechanism:
// layer-0 A-fragments bulk-gathered into per-wave LDS via global_load_lds
// (per-lane global src, wave-uniform LDS dst). A seg-pair chunk {c,K-1-c}
// (8x1KB) is issued up front and drained ONCE per chunk -- gather latency
// paid 1-2x/tile instead of once per phase. Dedup preserved (resident
// fragments serve fwd+bwd by LDS re-read). Gather region unions with act
// (temporally disjoint). Zero prefetch registers; only __syncthreads.
template <int K, int NHEAD>
__global__ __launch_bounds__(256, (K == 1) ? 4 : 3) void level_kernel(
    const unsigned short* __restrict__ hf,
    const int* __restrict__ idx,
    const unsigned short* __restrict__ pw,  // packed W0|W1|W2 (fp16 bits)
    const float* __restrict__ b0, const float* __restrict__ b1,
    const float* __restrict__ b2,
    const float* __restrict__ hw0, const float* __restrict__ hb0,
    float* __restrict__ out0,
    const float* __restrict__ hw1, const float* __restrict__ hb1,
    float* __restrict__ out1,
    const float* __restrict__ hw2, const float* __restrict__ hb2,
    float* __restrict__ out2,
    int N) {
  constexpr int NDIR = (K > 1) ? 2 : 1;
  constexpr int KT0 = 4 * K;
  constexpr int NC = (K + 1) / 2;              // seg-pair chunks
  constexpr int GRB = (K == 1) ? 4096 : 8192;  // gather/act bytes per wave
  constexpr int SMEM_SZ = 16384 + 4 * GRB;     // 48 KB (K>=2) / 32 KB (K==1)

  __shared__ __align__(16) unsigned char smem[SMEM_SZ];

  const int lane = threadIdx.x & 63;
  const int wid = threadIdx.x >> 6;   // 0..3
  const int lrow = lane & 15;
  const int kb = lane >> 4;

  unsigned short* const bst = reinterpret_cast<unsigned short*>(smem);  // 16 KB
  unsigned char* const gbase = smem + 16384 + wid * GRB;  // per-wave private

  int tile = blockIdx.x * 4 + wid;
  const int maxtile = N / 16 - 1;
  const bool wr = (tile <= maxtile);
  if (!wr) tile = maxtile;  // clamp: all waves hit barriers, only writers store

  int src[K];
  #pragma unroll
  for (int s = 0; s < K; ++s)
    src[s] = (K == 1) ? (tile * 16 + lrow)
                      : idx[(size_t)(tile * 16 + lrow) * K + s];

  // stage one 8 KB weight slab into bst half [buf]; each wave DMAs 2x1KB
  auto stage = [&](int buf, const unsigned short* slab) {
    const unsigned short* g = slab + (wid * 2) * 512 + lane * 8;
    unsigned short* l = bst + buf * 4096 + (wid * 2) * 512;
    __builtin_amdgcn_global_load_lds((gconst_t*)g, (lds_t*)l, 16, 0, 0);
    __builtin_amdgcn_global_load_lds((gconst_t*)(g + 512), (lds_t*)(l + 512), 16, 0, 0);
  };

  // gather DMA: fragment (seg,sub) -> 1KB slot. Per-lane global src,
  // wave-uniform LDS dst (HW writes lane l at dst + l*16).
  auto dma_gather = [&](int seg, int sub, int slot) {
    const unsigned short* g = hf + (size_t)src[seg] * 128 + sub * 32 + kb * 8;
    __builtin_amdgcn_global_load_lds((gconst_t*)g,
                                     (lds_t*)(gbase + slot * 1024), 16, 0, 0);
  };
  // chunk c: seg c -> slots 0-3; seg K-1-c -> slots 4-7 (if distinct)
  auto issue_chunk = [&](int c) {
    #pragma unroll
    for (int sub = 0; sub < 4; ++sub) {
      dma_gather(c, sub, sub);
      if (c != K - 1 - c) dma_gather(K - 1 - c, sub, 4 + sub);
    }
  };
  auto readfrag = [&](int slot) -> half8 {
    return *reinterpret_cast<const half8*>(gbase + slot * 1024 + lane * 16);
  };

  f32x4 acc[NDIR][8];
  auto zero_acc = [&]() {
    #pragma unroll
    for (int d = 0; d < NDIR; ++d)
      #pragma unroll
      for (int nt = 0; nt < 8; ++nt) acc[d][nt] = f32x4{0.f, 0.f, 0.f, 0.f};
  };

  auto mfma_phase = [&](int buf, half8 af, half8 ab) {
    #pragma unroll
    for (int nt = 0; nt < 8; ++nt) {
      half8 bq = *reinterpret_cast<const half8*>(bst + buf * 4096 + nt * 512 + lane * 8);
      acc[0][nt] = mfma16(af, bq, acc[0][nt]);
      if constexpr (NDIR == 2) acc[1][nt] = mfma16(ab, bq, acc[1][nt]);
    }
  };

  // layers 1/2: A from per-wave activation LDS (XOR-swizzled rows);
  // act region reuses the gather region (dead by then).
  auto actA = [&](int d, int kt) -> half8 {
    unsigned off = (unsigned)(lrow * 256 + (kt * 32 + kb * 8) * 2) ^
                   ((unsigned)(lrow & 7) << 4);
    return *reinterpret_cast<const half8*>(gbase + d * 4096 + off);
  };
  auto store_act = [&](int d, const float* bias) {
    unsigned char* base = gbase + d * 4096;
    #pragma unroll
    for (int nt = 0; nt < 8; ++nt) {
      float bv = bias[nt * 16 + lrow];
      #pragma unroll
      for (int r = 0; r < 4; ++r) {
        float v = fmaxf(acc[d][nt][r] + bv, 0.f);
        int trow = 4 * kb + r;
        unsigned off = (unsigned)(trow * 256 + (nt * 16 + lrow) * 2) ^
                       ((unsigned)(trow & 7) << 4);
        *reinterpret_cast<unsigned short*>(base + off) = f2h_bits(v);
      }
    }
  };

  zero_acc();
  const unsigned short* w1 = pw + (size_t)KT0 * 4096;

  // ================= layer 0: chunked bulk-gather ========================
  issue_chunk(0);
  stage(0, pw);   // slab (seg 0, sub 0)
  __syncthreads();

  int cur = 0;
  #pragma unroll
  for (int c = 0; c < NC; ++c) {
    const int sA = c, sB = K - 1 - c;
    const bool sp = (sA == sB);
    const int phc = sp ? 4 : 8;
    #pragma unroll 1
    for (int ph = 0; ph < phc; ++ph) {
      const int half = sp ? 0 : (ph >> 2);
      const int sub = ph & 3;
      const int fs = sp ? sub : (half * 4 + sub);
      const int bs = sp ? sub : ((1 - half) * 4 + sub);
      half8 af = readfrag(fs);
      half8 ab = af;
      if constexpr (NDIR == 2) ab = sp ? af : readfrag(bs);

      if (ph + 1 < phc) {
        const int h2 = sp ? 0 : ((ph + 1) >> 2);
        const int sub2 = (ph + 1) & 3;
        const int seg2 = h2 ? sB : sA;
        stage(cur ^ 1, pw + (size_t)(seg2 * 4 + sub2) * 4096);
      } else if (c + 1 < NC) {
        stage(cur ^ 1, pw + (size_t)((c + 1) * 4) * 4096);  // next chunk (segA,0)
      } else {
        stage(cur ^ 1, w1);  // layer-1 slab 0
      }
      mfma_phase(cur, af, ab);
      // reload gathers for the next chunk after this chunk's last MFMAs;
      // drained by this phase's barrier (region per-wave private).
      if (ph + 1 == phc && c + 1 < NC) issue_chunk(c + 1);
      __syncthreads();
      cur ^= 1;
    }
  }

  #pragma unroll
  for (int d = 0; d < NDIR; ++d) store_act(d, b0);

  // ================= layers 1 and 2 (round-6 8KB phases) =================
  #pragma unroll 1
  for (int layer = 1; layer <= 2; ++layer) {
    const unsigned short* w = (layer == 1) ? w1 : w1 + 16384;
    zero_acc();
    for (int kt = 0; kt < 4; ++kt) {
      if (kt + 1 < 4) stage(cur ^ 1, w + (size_t)(kt + 1) * 4096);
      else if (layer == 1) stage(cur ^ 1, w1 + 16384);  // layer-2 slab 0
      half8 a[NDIR];
      #pragma unroll
      for (int d = 0; d < NDIR; ++d) a[d] = actA(d, kt);
      #pragma unroll
      for (int nt = 0; nt < 8; ++nt) {
        half8 bq = *reinterpret_cast<const half8*>(bst + cur * 4096 + nt * 512 + lane * 8);
        #pragma unroll
        for (int d = 0; d < NDIR; ++d) acc[d][nt] = mfma16(a[d], bq, acc[d][nt]);
      }
      if (!(layer == 2 && kt == 3)) {  // last slab: no one reuses bst
        __syncthreads();
        cur ^= 1;
      }
    }
    if (layer == 1) {
      #pragma unroll
      for (int d = 0; d < NDIR; ++d) store_act(d, b1);
    }
  }

  // ================= epilogue: bias+relu(+pool), heads ===================
  f32x4 y[8];
  #pragma unroll
  for (int nt = 0; nt < 8; ++nt) {
    float bv = b2[nt * 16 + lrow];
    #pragma unroll
    for (int r = 0; r < 4; ++r) {
      float v = fmaxf(acc[0][nt][r] + bv, 0.f);
      if constexpr (NDIR == 2) v += fmaxf(acc[1][nt][r] + bv, 0.f);
      y[nt][r] = v;
    }
  }

  const float* hws[3] = {hw0, hw1, hw2};
  const float* hbs[3] = {hb0, hb1, hb2};
  float* outs[3] = {out0, out1, out2};
  #pragma unroll
  for (int hd = 0; hd < NHEAD; ++hd) {
    float p[4] = {0.f, 0.f, 0.f, 0.f};
    #pragma unroll
    for (int nt = 0; nt < 8; ++nt) {
      float w = hws[hd][nt * 16 + lrow];
      #pragma unroll
      for (int r = 0; r < 4; ++r) p[r] += y[nt][r] * w;
    }
    #pragma unroll
    for (int m = 1; m < 16; m <<= 1) {
      #pragma unroll
      for (int r = 0; r < 4; ++r) p[r] += __shfl_xor(p[r], m, 64);
    }
    if (wr && lrow < 4) {
      float pv = (lrow == 0) ? p[0] : (lrow == 1) ? p[1] : (lrow == 2) ? p[2] : p[3];
      outs[hd][tile * 16 + 4 * kb + lrow] = pv + hbs[hd][0];
    }
  }
}

// -------------------------------------------------------------------------
extern "C" void kernel_launch(void* const* d_in, const int* in_sizes, int n_in,
                              void* d_out, int out_size, void* d_ws, size_t ws_size,
                              hipStream_t stream) {
  (void)in_sizes; (void)n_in; (void)out_size;

  const float* h = (const float*)d_in[0];
  const int* idx2 = (const int*)d_in[1];
  const int* idx3 = (const int*)d_in[2];
  const int* idx4 = (const int*)d_in[3];

  const float* sW[4][3];
  const float* sb[4][3];
  for (int L = 0; L < 4; ++L)
    for (int j = 0; j < 3; ++j) {
      sW[L][j] = (const float*)d_in[4 + L * 6 + j * 2];
      sb[L][j] = (const float*)d_in[4 + L * 6 + j * 2 + 1];
    }
  // heads: h1_sigma, h1_epsilon, h1_q, h2_k, h2_eq, h3_k, h3_eq, h4_k, h4_eq
  const float* hW[9];
  const float* hB[9];
  for (int i = 0; i < 9; ++i) {
    hW[i] = (const float*)d_in[28 + i * 2];
    hB[i] = (const float*)d_in[28 + i * 2 + 1];
  }

  // workspace: fp16 h (12.8M elems) + packed weights (294912 elems)
  size_t need = ((size_t)N1_ * 128 + 294912) * 2;
  if (ws_size < need) return;
  unsigned short* hf = (unsigned short*)d_ws;
  unsigned short* pw = hf + (size_t)N1_ * 128;

  cvt_h_kernel<<<(N1_ * 128 / 4 + 255) / 256, 256, 0, stream>>>(h, hf, N1_ * 128 / 4);

  PackInfo pi;
  const int din[12] = {128, 128, 128, 256, 128, 128, 384, 128, 128, 512, 128, 128};
  int ktb = 0, ooff = 0;
  for (int m = 0; m < 12; ++m) {
    pi.W[m] = sW[m / 3][m % 3];
    pi.kt_base[m] = ktb;
    pi.out_off[m] = ooff;
    ktb += din[m] / 32;
    ooff += din[m] * 128;
  }
  pi.kt_base[12] = ktb;  // 72
  pack_w_kernel<<<ktb, 64, 0, stream>>>(pi, pw);

  float* out = (float*)d_out;
  float* o_sigma = out;
  float* o_eps = out + N1_;
  float* o_q = out + 2 * N1_;
  float* o_k2 = out + 3 * N1_;
  float* o_eq2 = o_k2 + N2_;
  float* o_k3 = o_eq2 + N2_;
  float* o_eq3 = o_k3 + N3_;
  float* o_k4 = o_eq3 + N3_;
  float* o_eq4 = o_k4 + N4_;

  // grid: each block covers 4 waves x 1 tile = 64 rows
  level_kernel<1, 3><<<(N1_ / 16 + 3) / 4, 256, 0, stream>>>(
      hf, nullptr, pw + pi.out_off[0], sb[0][0], sb[0][1], sb[0][2],
      hW[0], hB[0], o_sigma, hW[1], hB[1], o_eps, hW[2], hB[2], o_q, N1_);
  level_kernel<2, 2><<<(N2_ / 16 + 3) / 4, 256, 0, stream>>>(
      hf, idx2, pw + pi.out_off[3], sb[1][0], sb[1][1], sb[1][2],
      hW[3], hB[3], o_k2, hW[4], hB[4], o_eq2, nullptr, nullptr, nullptr, N2_);
  level_kernel<3, 2><<<(N3_ / 16 + 3) / 4, 256, 0, stream>>>(
      hf, idx3, pw + pi.out_off[6], sb[2][0], sb[2][1], sb[2][2],
      hW[5], hB[5], o_k3, hW[6], hB[6], o_eq3, nullptr, nullptr, nullptr, N3_);
  level_kernel<4, 2><<<(N4_ / 16 + 3) / 4, 256, 0, stream>>>(
      hf, idx4, pw + pi.out_off[9], sb[3][0], sb[3][1], sb[3][2],
      hW[7], hB[7], o_k4, hW[8], hB[8], o_eq4, nullptr, nullptr, nullptr, N4_);
}